// Round 10
// baseline (754.806 us; speedup 1.0000x reference)
//
#include <hip/hip_runtime.h>
#include <hip/hip_bf16.h>
#include <math.h>

#define BATCH 256
#define SEQ   512
#define INS   300
#define KP    320   // K padded to 10 x 32 (xg gemm)
#define HID   128
#define NG    384   // 3*HID

typedef __attribute__((ext_vector_type(8))) short short8;   // 8 x bf16 (4 VGPRs)
typedef __attribute__((ext_vector_type(4))) float f32x4;

// ---------- helpers ----------
__device__ __forceinline__ float bf2f(unsigned short u) {
    unsigned int v = ((unsigned int)u) << 16;
    return __uint_as_float(v);
}
__device__ __forceinline__ unsigned short f2bf(float f) {
    unsigned int u = __float_as_uint(f);
    unsigned int r = (u + 0x7FFFu + ((u >> 16) & 1u)) >> 16;
    return (unsigned short)r;
}

// ---------- Kernel 0: split W_ih (fp32 384x300) -> bf16 hi/lo planes (384x320, k-padded) ----------
__global__ void conv_wih(const float* __restrict__ Wih,
                         unsigned short* __restrict__ Whi,
                         unsigned short* __restrict__ Wlo)
{
    int idx = blockIdx.x * 256 + threadIdx.x;     // 0 .. 384*320-1
    if (idx >= NG * KP) return;
    int g = idx / KP, k = idx - g * KP;
    float v = (k < INS) ? Wih[g * INS + k] : 0.f;
    unsigned short h = f2bf(v);
    float r = v - bf2f(h);
    Whi[idx] = h;
    Wlo[idx] = f2bf(r);
}

// ---------- Kernel A: xg = x @ W_ih^T + b_ih, 2-pass, 64-row tile ----------
// r9 A/B: cutting xg MFMAs 1/3 changed NOTHING -> not issue-bound. Register
// audit: 128-row tile needs ~180 live VGPR under a 128 cap (launch_bounds
// 512,2) => ~50 VGPR spilled inside the ks-loop => scratch HBM round-trips
// dominate (~10x roofline). Fix: 64-row tile, acc[2][6]=48 VGPR, B-frags
// JIT-loaded per ni (8 live VGPR) => ~90 total, NO spill, 2 blocks/CU.
// x still read exactly once (grid 2048 x 64 rows). Per-(mi,ni) MFMA chain
// order identical to r9 => bitwise-identical xg.
template <bool BF16OUT>
__launch_bounds__(512, 2)
__global__ void xg_fused(const float* __restrict__ x,
                         const unsigned short* __restrict__ Whi,
                         const unsigned short* __restrict__ Wlo,
                         const float* __restrict__ bih,
                         void* __restrict__ xg_out,
                         int t0, int CT)
{
    __shared__ unsigned short Ah[64][40];   // 5 KiB, +8 pad: 2-way-max bank aliasing

    const int tid  = threadIdx.x;
    const int lane = tid & 63;
    const int w    = tid >> 6;          // 0..7
    const int wm   = (w & 1) * 32;      // M half (of 64)
    const int wn   = (w >> 1) * 96;     // N quarter
    const int m0   = blockIdx.x * 64;

    const int srow = tid >> 3;          // 0..63
    const int kq   = tid & 7;           // 0..7, 4 k each
    const int rr = m0 + srow;
    const int bb = rr / CT;
    const float* xrow = x + (size_t)(bb * SEQ + t0 + (rr - bb * CT)) * INS;

    const int lmf = lane & 15;
    const int lk  = (lane >> 4) * 8;

    f32x4 acc[2][6] = {};

    float av[4];
    auto loadA = [&](int ks) {
        const int k0 = ks * 32 + kq * 4;
        if (k0 + 4 <= INS) {
            float4 f = *(const float4*)(xrow + k0);
            av[0] = f.x; av[1] = f.y; av[2] = f.z; av[3] = f.w;
        } else {
            #pragma unroll
            for (int i = 0; i < 4; i++)
                av[i] = (k0 + i < INS) ? xrow[k0 + i] : 0.f;
        }
    };
    loadA(0);

    for (int ks = 0; ks < KP / 32; ks++) {
        __syncthreads();   // prev k-step's A-frag reads done; safe to overwrite
        {
            union { unsigned short us[4]; uint2 q; } ph;
            #pragma unroll
            for (int i = 0; i < 4; i++)
                ph.us[i] = f2bf(av[i]);
            *(uint2*)&Ah[srow][kq * 4] = ph.q;
        }
        if (ks + 1 < KP / 32) loadA(ks + 1);   // T14: issue next slab before barrier
        __syncthreads();

        short8 ah[2];
        #pragma unroll
        for (int mi = 0; mi < 2; mi++)
            ah[mi] = *(const short8*)&Ah[wm + mi * 16 + lmf][lk];
        #pragma unroll
        for (int ni = 0; ni < 6; ni++) {       // JIT B loads: 8 live frag VGPRs
            const size_t off = (size_t)(wn + ni * 16 + lmf) * KP + ks * 32 + lk;
            short8 bh = *(const short8*)(Whi + off);
            short8 bl = *(const short8*)(Wlo + off);
            #pragma unroll
            for (int mi = 0; mi < 2; mi++) {
                acc[mi][ni] = __builtin_amdgcn_mfma_f32_16x16x32_bf16(ah[mi], bh, acc[mi][ni], 0, 0, 0);
                acc[mi][ni] = __builtin_amdgcn_mfma_f32_16x16x32_bf16(ah[mi], bl, acc[mi][ni], 0, 0, 0);
            }
        }
    }

    const int crow = (lane >> 4) * 4;
    #pragma unroll
    for (int ni = 0; ni < 6; ni++) {
        const int col = wn + ni * 16 + lmf;
        const float bias = bih[col];
        #pragma unroll
        for (int mi = 0; mi < 2; mi++) {
            #pragma unroll
            for (int i = 0; i < 4; i++) {
                const size_t row = (size_t)(m0 + wm + mi * 16 + crow + i);
                const float val = acc[mi][ni][i] + bias;
                if (BF16OUT) ((unsigned short*)xg_out)[row * NG + col] = f2bf(val);
                else         ((float*)xg_out)[row * NG + col] = val;
            }
        }
    }
}

// ---------- Kernel B: MFMA recurrence, 8 waves (2/SIMD) — r7/r9 verbatim ----------
// 8 waves x 3 tiles {w, 8+w, 16+w} (48 cols each), 24 MFMA/step/wave; two
// waves/SIMD interleave so one wave's activation/LDS/barrier hides under the
// other's MFMAs. hbuf plane stride 320B: conflict-free. Activation: lanes
// 0-15, j=16w+lm. Proven: ~319 us (r9).
template <bool BF16XG>
__launch_bounds__(512, 2)
__global__ void gru_mfma(const void* __restrict__ xg_in,
                         const float* __restrict__ Whh,
                         const float* __restrict__ bhh,
                         float* __restrict__ hstate,
                         int t0, int CT, int initial, int final_chunk,
                         const float* __restrict__ Wout,
                         const float* __restrict__ bout,
                         float* __restrict__ out)
{
    const int b    = blockIdx.x;
    const int tid  = threadIdx.x;
    const int w    = tid >> 6;          // 0..7
    const int lane = tid & 63;
    const int lm   = lane & 15;
    const int quad = lane >> 4;

    __shared__ alignas(16) unsigned short hbuf[2][2][160]; // [dbuf][hi/lo][j], 320B plane stride
    __shared__ float red[2 * HID];

    // wave w's 3 N-tiles (16 gate-cols each): r: w, z: 8+w, n: 16+w
    const int mts[3] = {w, 8 + w, 16 + w};

    // ---- persistent B fragments: B[k=32kt+quad*8+j][n=tile*16+lm] = Whh[n][k] ----
    short8 w_hi[3][4], w_lo[3][4];
    #pragma unroll
    for (int t = 0; t < 3; t++) {
        const float* wrow = Whh + (size_t)(mts[t] * 16 + lm) * HID + quad * 8;
        #pragma unroll
        for (int kt = 0; kt < 4; kt++) {
            float4 f0 = *(const float4*)(wrow + kt * 32);
            float4 f1 = *(const float4*)(wrow + kt * 32 + 4);
            float vv[8] = {f0.x, f0.y, f0.z, f0.w, f1.x, f1.y, f1.z, f1.w};
            short8 h8, l8;
            #pragma unroll
            for (int i = 0; i < 8; i++) {
                unsigned short h = f2bf(vv[i]);
                h8[i] = (short)h;
                l8[i] = (short)f2bf(vv[i] - bf2f(h));
            }
            w_hi[t][kt] = h8;
            w_lo[t][kt] = l8;
        }
    }

    // ---- per-activation-lane state: lanes 0-15 of wave w own j = 16w + lm ----
    const int jd = w * 16 + lm;
    float hprev = 0.f, bhr = 0.f, bhz = 0.f, bhn = 0.f, wo0 = 0.f, wo1 = 0.f;
    float nx0r = 0.f, nx0z = 0.f, nx0n = 0.f;   // xg for even steps
    float nx1r = 0.f, nx1z = 0.f, nx1n = 0.f;   // xg for odd steps
    const float* xgf = (const float*)xg_in;
    const unsigned short* xgb = (const unsigned short*)xg_in;

    if (lane < 16) {
        float h0 = initial ? 0.f : hstate[b * HID + jd];
        hprev = h0;
        bhr = bhh[jd]; bhz = bhh[HID + jd]; bhn = bhh[2 * HID + jd];
        wo0 = Wout[jd]; wo1 = Wout[HID + jd];
        unsigned short hh = f2bf(h0);
        hbuf[0][0][jd] = hh;
        hbuf[0][1][jd] = f2bf(h0 - bf2f(hh));
        const size_t nb0 = (size_t)b * CT * NG;
        const size_t nb1 = nb0 + NG;
        if (BF16XG) {
            nx0r = bf2f(xgb[nb0 + jd]); nx0z = bf2f(xgb[nb0 + HID + jd]); nx0n = bf2f(xgb[nb0 + 2 * HID + jd]);
            nx1r = bf2f(xgb[nb1 + jd]); nx1z = bf2f(xgb[nb1 + HID + jd]); nx1n = bf2f(xgb[nb1 + 2 * HID + jd]);
        } else {
            nx0r = xgf[nb0 + jd]; nx0z = xgf[nb0 + HID + jd]; nx0n = xgf[nb0 + 2 * HID + jd];
            nx1r = xgf[nb1 + jd]; nx1z = xgf[nb1 + HID + jd]; nx1n = xgf[nb1 + 2 * HID + jd];
        }
    }
    __syncthreads();

    // A-frag plane select: rows lm in {1,5,9,13} read h_lo, others h_hi
    // => every quad's C regs 0/1 = (hh*W, hl*W) for its col lm
    const int psel = ((lm & 3) == 1) ? 1 : 0;

    const f32x4 z4 = {0.f, 0.f, 0.f, 0.f};     // loop-invariant zero C-in

// one GRU timestep; P = compile-time dbuf index, T = runtime step, NX* = its xg regs
#define GRU_STEP(P, T, NXR, NXZ, NXN)                                                             \
    {                                                                                             \
        short8 a2[4];                                                                             \
        _Pragma("unroll")                                                                         \
        for (int kt = 0; kt < 4; kt++)                                                            \
            a2[kt] = *(const short8*)&hbuf[P][psel][kt * 32 + quad * 8];                          \
        f32x4 acc[3];                                                                             \
        _Pragma("unroll")                                                                         \
        for (int t = 0; t < 3; t++)                                                               \
            acc[t] = __builtin_amdgcn_mfma_f32_16x16x32_bf16(a2[0], w_hi[t][0], z4, 0, 0, 0);     \
        _Pragma("unroll")                                                                         \
        for (int kt = 1; kt < 4; kt++) {                                                          \
            _Pragma("unroll")                                                                     \
            for (int t = 0; t < 3; t++)                                                           \
                acc[t] = __builtin_amdgcn_mfma_f32_16x16x32_bf16(a2[kt], w_hi[t][kt], acc[t], 0, 0, 0); \
        }                                                                                         \
        _Pragma("unroll")                                                                         \
        for (int kt = 0; kt < 4; kt++) {                                                          \
            _Pragma("unroll")                                                                     \
            for (int t = 0; t < 3; t++)                                                           \
                acc[t] = __builtin_amdgcn_mfma_f32_16x16x32_bf16(a2[kt], w_lo[t][kt], acc[t], 0, 0, 0); \
        }                                                                                         \
        if (lane < 16) {                                                                          \
            float hgr = (acc[0][0] + acc[0][1]) + bhr;                                            \
            float hgz = (acc[1][0] + acc[1][1]) + bhz;                                            \
            float hgn = (acc[2][0] + acc[2][1]) + bhn;                                            \
            float rg = __builtin_amdgcn_rcpf(1.f + __expf(-((NXR) + hgr)));                       \
            float zg = __builtin_amdgcn_rcpf(1.f + __expf(-((NXZ) + hgz)));                       \
            float nv = (NXN) + rg * hgn;                                                          \
            float e  = __expf(2.f * nv);                                                          \
            float ng = 1.f - 2.f * __builtin_amdgcn_rcpf(e + 1.f);                                \
            hprev = (1.f - zg) * ng + zg * hprev;                                                 \
            unsigned short hh = f2bf(hprev);                                                      \
            hbuf[1 - (P)][0][jd] = hh;                                                            \
            hbuf[1 - (P)][1][jd] = f2bf(hprev - bf2f(hh));                                        \
            if ((T) + 2 < CT) {   /* prefetch distance 2; stays in flight across barriers */      \
                const size_t nb = ((size_t)b * CT + (T) + 2) * NG;                                \
                if (BF16XG) { NXR = bf2f(xgb[nb + jd]); NXZ = bf2f(xgb[nb + HID + jd]); NXN = bf2f(xgb[nb + 2 * HID + jd]); } \
                else        { NXR = xgf[nb + jd];       NXZ = xgf[nb + HID + jd];       NXN = xgf[nb + 2 * HID + jd]; }       \
            }                                                                                     \
        }                                                                                         \
        asm volatile("s_waitcnt lgkmcnt(0)\ns_barrier" ::: "memory");                             \
    }

    for (int tt = 0; tt < CT; tt += 2) {      // CT is a power of two >= 64
        GRU_STEP(0, tt,     nx0r, nx0z, nx0n)
        GRU_STEP(1, tt + 1, nx1r, nx1z, nx1n)
    }
#undef GRU_STEP

    if (lane < 16) hstate[b * HID + jd] = hprev;

    // ---- head: relu -> 2-class linear -> log_softmax (identical reduction tree) ----
    if (final_chunk) {
        if (lane < 16) {
            float f = hprev > 0.f ? hprev : 0.f;
            red[jd] = f * wo0;
            red[HID + jd] = f * wo1;
        }
        __syncthreads();
        if (tid < 64) {
            float l0 = red[tid] + red[64 + tid];
            float l1 = red[HID + tid] + red[HID + 64 + tid];
            #pragma unroll
            for (int d = 32; d > 0; d >>= 1) {
                l0 += __shfl_down(l0, d, 64);
                l1 += __shfl_down(l1, d, 64);
            }
            if (tid == 0) {
                l0 += bout[0]; l1 += bout[1];
                float m = fmaxf(l0, l1);
                float lse = m + logf(__expf(l0 - m) + __expf(l1 - m));
                out[b * 2 + 0] = l0 - lse;
                out[b * 2 + 1] = l1 - lse;
            }
        }
    }
}

// ---------- launch ----------
extern "C" void kernel_launch(void* const* d_in, const int* in_sizes, int n_in,
                              void* d_out, int out_size, void* d_ws, size_t ws_size,
                              hipStream_t stream) {
    const float* x    = (const float*)d_in[0];
    const float* Wih  = (const float*)d_in[1];
    const float* Whh  = (const float*)d_in[2];
    const float* bih  = (const float*)d_in[3];
    const float* bhh  = (const float*)d_in[4];
    const float* Wout = (const float*)d_in[5];
    const float* bout = (const float*)d_in[6];
    float* out = (float*)d_out;

    // ws layout: [W_hi | W_lo | hstate | xg]
    unsigned short* Whi = (unsigned short*)d_ws;                       // 384*320*2 = 245760 B
    unsigned short* Wlo = (unsigned short*)((char*)d_ws + 245760);
    float* hstate = (float*)((char*)d_ws + 491520);                    // 128 KiB
    void*  xg     = (void*)((char*)d_ws + 622592);
    const size_t avail = ws_size > 622592 ? ws_size - 622592 : 0;

    bool bf16;
    int CT;
    if (avail >= (size_t)BATCH * SEQ * NG * 4) {        // fp32 xg (201 MB)
        bf16 = false; CT = SEQ;
    } else if (avail >= (size_t)BATCH * SEQ * NG * 2) { // bf16 xg (100 MB)
        bf16 = true;  CT = SEQ;
    } else {                                            // chunked bf16
        bf16 = true;
        CT = 64;
        while (CT * 2 <= SEQ && avail >= (size_t)BATCH * (size_t)(CT * 2) * NG * 2) CT *= 2;
    }

    conv_wih<<<(NG * KP + 255) / 256, 256, 0, stream>>>(Wih, Whi, Wlo);

    for (int t0 = 0; t0 < SEQ; t0 += CT) {
        dim3 gridA((BATCH * CT) / 64);
        const int initial = (t0 == 0);
        const int final_chunk = (t0 + CT >= SEQ);
        if (bf16) {
            xg_fused<true><<<gridA, 512, 0, stream>>>(x, Whi, Wlo, bih, xg, t0, CT);
            gru_mfma<true><<<BATCH, 512, 0, stream>>>(xg, Whh, bhh, hstate, t0, CT,
                                                      initial, final_chunk, Wout, bout, out);
        } else {
            xg_fused<false><<<gridA, 512, 0, stream>>>(x, Whi, Wlo, bih, xg, t0, CT);
            gru_mfma<false><<<BATCH, 512, 0, stream>>>(xg, Whh, bhh, hstate, t0, CT,
                                                       initial, final_chunk, Wout, bout, out);
        }
    }
}

// Round 11
// 571.989 us; speedup vs baseline: 1.3196x; 1.3196x over previous
//
#include <hip/hip_runtime.h>
#include <hip/hip_fp16.h>
#include <math.h>

#define BATCH 256
#define SEQ   512
#define INS   300
#define KP    320   // K padded to 10 x 32 (xg gemm)
#define HID   128
#define NG    384   // 3*HID

typedef __attribute__((ext_vector_type(8))) _Float16 half8;  // 8 x fp16 (4 VGPRs)
typedef __attribute__((ext_vector_type(4))) float f32x4;

// ---------- helpers ----------
__device__ __forceinline__ unsigned short f2h(float f) {
    union { _Float16 h; unsigned short u; } c;
    c.h = (_Float16)f;          // RTNE
    return c.u;
}
__device__ __forceinline__ float h2f(unsigned short u) {
    union { unsigned short u; _Float16 h; } c;
    c.u = u;
    return (float)c.h;
}

// ---------- Kernel 0: W_ih (fp32 384x300) -> fp16 plane (384x320, k-padded) ----------
// |W| <= 0.088 -> fp16 rel err 2^-11; single plane replaces bf16 hi/lo pair.
__global__ void conv_wih(const float* __restrict__ Wih,
                         unsigned short* __restrict__ Whf)
{
    int idx = blockIdx.x * 256 + threadIdx.x;     // 0 .. 384*320-1
    if (idx >= NG * KP) return;
    int g = idx / KP, k = idx - g * KP;
    float v = (k < INS) ? Wih[g * INS + k] : 0.f;
    Whf[idx] = f2h(v);
}

// ---------- Kernel A: xg = x @ W_ih^T + b_ih, single-pass fp16 ----------
// r9 structure (128-row tile, B preloaded before barrier — r10's JIT loads
// serialized L2 latency and regressed; reverted). fp16 halves MFMA count
// (1 per (mi,ni)) and B traffic vs the bf16 2-pass. LB(512,2) caps VGPR at
// 256 (m69 buckets — r10's 128-cap assumption was wrong); ~160 live, no spill.
// xg stored fp16: storage err 2^-11 (was bf16 2^-9 — the r8/r9 absmax source).
__launch_bounds__(512, 2)
__global__ void xg_fused(const float* __restrict__ x,
                         const unsigned short* __restrict__ Whf,
                         const float* __restrict__ bih,
                         unsigned short* __restrict__ xg_out,
                         int t0, int CT)
{
    __shared__ unsigned short Ah[128][40];   // 10 KiB fp16 staging

    const int tid  = threadIdx.x;
    const int lane = tid & 63;
    const int w    = tid >> 6;          // 0..7
    const int wm   = (w & 1) * 64;      // M half
    const int wn   = (w >> 1) * 96;     // N quarter
    const int m0   = blockIdx.x * 128;

    const int srow = tid >> 2;          // 0..127
    const int kq   = tid & 3;           // 0..3, 8 k each
    const int rr = m0 + srow;
    const int bb = rr / CT;
    const float* xrow = x + (size_t)(bb * SEQ + t0 + (rr - bb * CT)) * INS;

    const int lmf = lane & 15;
    const int lk  = (lane >> 4) * 8;

    f32x4 acc[4][6] = {};

    float av[8];
    auto loadA = [&](int ks) {
        const int k0 = ks * 32 + kq * 8;
        if (k0 + 8 <= INS) {
            float4 f0 = *(const float4*)(xrow + k0);
            float4 f1 = *(const float4*)(xrow + k0 + 4);
            av[0] = f0.x; av[1] = f0.y; av[2] = f0.z; av[3] = f0.w;
            av[4] = f1.x; av[5] = f1.y; av[6] = f1.z; av[7] = f1.w;
        } else {
            #pragma unroll
            for (int i = 0; i < 8; i++)
                av[i] = (k0 + i < INS) ? xrow[k0 + i] : 0.f;
        }
    };
    loadA(0);

    for (int ks = 0; ks < KP / 32; ks++) {
        // B frags for this k-slab: issue early, straight from global (L2-hot).
        half8 bh[6];
        #pragma unroll
        for (int ni = 0; ni < 6; ni++) {
            const size_t off = (size_t)(wn + ni * 16 + lmf) * KP + ks * 32 + lk;
            bh[ni] = *(const half8*)(Whf + off);
        }

        __syncthreads();   // prev k-step's A-frag reads done; safe to overwrite
        {
            union { unsigned short us[8]; uint4 q; } ph;
            #pragma unroll
            for (int i = 0; i < 8; i++)
                ph.us[i] = f2h(av[i]);
            *(uint4*)&Ah[srow][kq * 8] = ph.q;
        }
        if (ks + 1 < KP / 32) loadA(ks + 1);   // issue next slab before barrier
        __syncthreads();

        half8 ah[4];
        #pragma unroll
        for (int mi = 0; mi < 4; mi++)
            ah[mi] = *(const half8*)&Ah[wm + mi * 16 + lmf][lk];
        #pragma unroll
        for (int ni = 0; ni < 6; ni++) {
            #pragma unroll
            for (int mi = 0; mi < 4; mi++)
                acc[mi][ni] = __builtin_amdgcn_mfma_f32_16x16x32_f16(ah[mi], bh[ni], acc[mi][ni], 0, 0, 0);
        }
    }

    const int crow = (lane >> 4) * 4;
    #pragma unroll
    for (int ni = 0; ni < 6; ni++) {
        const int col = wn + ni * 16 + lmf;
        const float bias = bih[col];
        #pragma unroll
        for (int mi = 0; mi < 4; mi++) {
            #pragma unroll
            for (int i = 0; i < 4; i++) {
                const size_t row = (size_t)(m0 + wm + mi * 16 + crow + i);
                xg_out[row * NG + col] = f2h(acc[mi][ni][i] + bias);
            }
        }
    }
}

// ---------- Kernel B: MFMA recurrence, 8 waves (2/SIMD), single-pass fp16 ----------
// r9 counters: step 1495 cyc with 931 cyc MFMA pipe (2 waves x 24 x 19.4)
// => MFMA-pipe-bound. fp16 single plane (|h|<1, |Whh|<=0.088: rel err 2^-11,
// tighter than the bf16 hi/lo pair) halves it: 12 MFMA/wave/step, pipe 466 cyc.
// No psel plane trick needed: all A rows = h; quad0 reg0 = result.
// hbuf[2][160] fp16 (320B buffer stride): conflict-free as measured (r4+).
__launch_bounds__(512, 2)
__global__ void gru_mfma(const unsigned short* __restrict__ xg_in,
                         const float* __restrict__ Whh,
                         const float* __restrict__ bhh,
                         float* __restrict__ hstate,
                         int t0, int CT, int initial, int final_chunk,
                         const float* __restrict__ Wout,
                         const float* __restrict__ bout,
                         float* __restrict__ out)
{
    const int b    = blockIdx.x;
    const int tid  = threadIdx.x;
    const int w    = tid >> 6;          // 0..7
    const int lane = tid & 63;
    const int lm   = lane & 15;
    const int quad = lane >> 4;

    __shared__ alignas(16) unsigned short hbuf[2][160]; // [dbuf][j] fp16, 320B stride
    __shared__ float red[2 * HID];

    // wave w's 3 N-tiles (16 gate-cols each): r: w, z: 8+w, n: 16+w
    const int mts[3] = {w, 8 + w, 16 + w};

    // ---- persistent B fragments: B[k=32kt+quad*8+j][n=tile*16+lm] = Whh[n][k] ----
    half8 w_h[3][4];
    #pragma unroll
    for (int t = 0; t < 3; t++) {
        const float* wrow = Whh + (size_t)(mts[t] * 16 + lm) * HID + quad * 8;
        #pragma unroll
        for (int kt = 0; kt < 4; kt++) {
            float4 f0 = *(const float4*)(wrow + kt * 32);
            float4 f1 = *(const float4*)(wrow + kt * 32 + 4);
            half8 h8;
            h8[0] = (_Float16)f0.x; h8[1] = (_Float16)f0.y;
            h8[2] = (_Float16)f0.z; h8[3] = (_Float16)f0.w;
            h8[4] = (_Float16)f1.x; h8[5] = (_Float16)f1.y;
            h8[6] = (_Float16)f1.z; h8[7] = (_Float16)f1.w;
            w_h[t][kt] = h8;
        }
    }

    // ---- per-activation-lane state: lanes 0-15 of wave w own j = 16w + lm ----
    const int jd = w * 16 + lm;
    float hprev = 0.f, bhr = 0.f, bhz = 0.f, bhn = 0.f, wo0 = 0.f, wo1 = 0.f;
    float nx0r = 0.f, nx0z = 0.f, nx0n = 0.f;   // xg for even steps
    float nx1r = 0.f, nx1z = 0.f, nx1n = 0.f;   // xg for odd steps

    if (lane < 16) {
        float h0 = initial ? 0.f : hstate[b * HID + jd];
        hprev = h0;
        bhr = bhh[jd]; bhz = bhh[HID + jd]; bhn = bhh[2 * HID + jd];
        wo0 = Wout[jd]; wo1 = Wout[HID + jd];
        hbuf[0][jd] = f2h(h0);
        const size_t nb0 = (size_t)b * CT * NG;
        const size_t nb1 = nb0 + NG;
        nx0r = h2f(xg_in[nb0 + jd]); nx0z = h2f(xg_in[nb0 + HID + jd]); nx0n = h2f(xg_in[nb0 + 2 * HID + jd]);
        nx1r = h2f(xg_in[nb1 + jd]); nx1z = h2f(xg_in[nb1 + HID + jd]); nx1n = h2f(xg_in[nb1 + 2 * HID + jd]);
    }
    __syncthreads();

    const f32x4 z4 = {0.f, 0.f, 0.f, 0.f};     // loop-invariant zero C-in

// one GRU timestep; P = compile-time dbuf index, T = runtime step, NX* = its xg regs
#define GRU_STEP(P, T, NXR, NXZ, NXN)                                                             \
    {                                                                                             \
        half8 a2[4];                                                                              \
        _Pragma("unroll")                                                                         \
        for (int kt = 0; kt < 4; kt++)                                                            \
            a2[kt] = *(const half8*)&hbuf[P][kt * 32 + quad * 8];                                 \
        f32x4 ar, az, an;                                                                         \
        ar = __builtin_amdgcn_mfma_f32_16x16x32_f16(a2[0], w_h[0][0], z4, 0, 0, 0);               \
        az = __builtin_amdgcn_mfma_f32_16x16x32_f16(a2[0], w_h[1][0], z4, 0, 0, 0);               \
        an = __builtin_amdgcn_mfma_f32_16x16x32_f16(a2[0], w_h[2][0], z4, 0, 0, 0);               \
        _Pragma("unroll")                                                                         \
        for (int kt = 1; kt < 4; kt++) {                                                          \
            ar = __builtin_amdgcn_mfma_f32_16x16x32_f16(a2[kt], w_h[0][kt], ar, 0, 0, 0);         \
            az = __builtin_amdgcn_mfma_f32_16x16x32_f16(a2[kt], w_h[1][kt], az, 0, 0, 0);         \
            an = __builtin_amdgcn_mfma_f32_16x16x32_f16(a2[kt], w_h[2][kt], an, 0, 0, 0);         \
        }                                                                                         \
        if (lane < 16) {                                                                          \
            /* all A rows = h -> quad0 reg0 = full col dot */                                     \
            float hgr = ar[0] + bhr;                                                              \
            float hgz = az[0] + bhz;                                                              \
            float hgn = an[0] + bhn;                                                              \
            float rg = __builtin_amdgcn_rcpf(1.f + __expf(-((NXR) + hgr)));                       \
            float zg = __builtin_amdgcn_rcpf(1.f + __expf(-((NXZ) + hgz)));                       \
            float nv = (NXN) + rg * hgn;                                                          \
            float e  = __expf(2.f * nv);                                                          \
            float ng = 1.f - 2.f * __builtin_amdgcn_rcpf(e + 1.f);                                \
            hprev = (1.f - zg) * ng + zg * hprev;                                                 \
            hbuf[1 - (P)][jd] = f2h(hprev);                                                       \
            if ((T) + 2 < CT) {   /* prefetch distance 2; stays in flight across barriers */      \
                const size_t nb = ((size_t)b * CT + (T) + 2) * NG;                                \
                NXR = h2f(xg_in[nb + jd]); NXZ = h2f(xg_in[nb + HID + jd]); NXN = h2f(xg_in[nb + 2 * HID + jd]); \
            }                                                                                     \
        }                                                                                         \
        asm volatile("s_waitcnt lgkmcnt(0)\ns_barrier" ::: "memory");                             \
    }

    for (int tt = 0; tt < CT; tt += 2) {      // CT is a power of two >= 64
        GRU_STEP(0, tt,     nx0r, nx0z, nx0n)
        GRU_STEP(1, tt + 1, nx1r, nx1z, nx1n)
    }
#undef GRU_STEP

    if (lane < 16) hstate[b * HID + jd] = hprev;

    // ---- head: relu -> 2-class linear -> log_softmax (identical reduction tree) ----
    if (final_chunk) {
        if (lane < 16) {
            float f = hprev > 0.f ? hprev : 0.f;
            red[jd] = f * wo0;
            red[HID + jd] = f * wo1;
        }
        __syncthreads();
        if (tid < 64) {
            float l0 = red[tid] + red[64 + tid];
            float l1 = red[HID + tid] + red[HID + 64 + tid];
            #pragma unroll
            for (int d = 32; d > 0; d >>= 1) {
                l0 += __shfl_down(l0, d, 64);
                l1 += __shfl_down(l1, d, 64);
            }
            if (tid == 0) {
                l0 += bout[0]; l1 += bout[1];
                float m = fmaxf(l0, l1);
                float lse = m + logf(__expf(l0 - m) + __expf(l1 - m));
                out[b * 2 + 0] = l0 - lse;
                out[b * 2 + 1] = l1 - lse;
            }
        }
    }
}

// ---------- launch ----------
extern "C" void kernel_launch(void* const* d_in, const int* in_sizes, int n_in,
                              void* d_out, int out_size, void* d_ws, size_t ws_size,
                              hipStream_t stream) {
    const float* x    = (const float*)d_in[0];
    const float* Wih  = (const float*)d_in[1];
    const float* Whh  = (const float*)d_in[2];
    const float* bih  = (const float*)d_in[3];
    const float* bhh  = (const float*)d_in[4];
    const float* Wout = (const float*)d_in[5];
    const float* bout = (const float*)d_in[6];
    float* out = (float*)d_out;

    // ws layout: [W_fp16 | hstate | xg(fp16)]
    unsigned short* Whf = (unsigned short*)d_ws;                       // 384*320*2 = 245760 B
    float* hstate = (float*)((char*)d_ws + 245760);                    // 128 KiB
    unsigned short* xg = (unsigned short*)((char*)d_ws + 376832);
    const size_t avail = ws_size > 376832 ? ws_size - 376832 : 0;

    // largest power-of-two chunk whose fp16 xg buffer fits (full SEQ = 100 MB)
    int CT = SEQ;
    while (CT > 4 && avail < (size_t)BATCH * CT * NG * 2) CT >>= 1;

    conv_wih<<<(NG * KP + 255) / 256, 256, 0, stream>>>(Wih, Whf);

    for (int t0 = 0; t0 < SEQ; t0 += CT) {
        dim3 gridA((BATCH * CT) / 128);
        const int initial = (t0 == 0);
        const int final_chunk = (t0 + CT >= SEQ);
        xg_fused<<<gridA, 512, 0, stream>>>(x, Whf, bih, xg, t0, CT);
        gru_mfma<<<BATCH, 512, 0, stream>>>(xg, Whh, bhh, hstate, t0, CT,
                                            initial, final_chunk, Wout, bout, out);
    }
}